// Round 8
// baseline (92.770 us; speedup 1.0000x reference)
//
#include <hip/hip_runtime.h>
#include <hip/hip_bf16.h>
#include <stdint.h>

typedef __attribute__((ext_vector_type(8))) short bf8_t;    // 8 bf16 in 4 VGPRs
typedef __attribute__((ext_vector_type(4))) short s4_t;
typedef __attribute__((ext_vector_type(4))) float f4_t;
typedef __attribute__((ext_vector_type(16))) float f16x_t;  // 32x32 mfma acc
typedef unsigned short u16;

#define GLOAD16(g, l) __builtin_amdgcn_global_load_lds(                                  \
    (const __attribute__((address_space(1))) void*)(g),                                  \
    (__attribute__((address_space(3))) void*)(l), 16, 0, 0)

__device__ __forceinline__ u16 f2bf(float f) {
    union { float f; unsigned u; } c; c.f = f;
    unsigned u = c.u;
    return (u16)((u + 0x7fffu + ((u >> 16) & 1u)) >> 16);   // RNE, inputs finite
}

__device__ __forceinline__ unsigned cvt_pk_bf16(float lo, float hi_) {
    unsigned r;
    asm("v_cvt_pk_bf16_f32 %0, %1, %2" : "=v"(r) : "v"(lo), "v"(hi_));
    return r;                                                // lo -> bits[15:0]
}

// ---------------- weights -> bf16 ----------------
__global__ void prep_kernel(const float* __restrict__ wq, const float* __restrict__ wk,
                            const float* __restrict__ wv, const float* __restrict__ wp,
                            const float* __restrict__ bq, const float* __restrict__ bk,
                            const float* __restrict__ bv,
                            u16* __restrict__ wcat, u16* __restrict__ wpb,
                            float* __restrict__ biasc) {
    int idx = blockIdx.x * 256 + threadIdx.x;
    if (idx < 196608) {                 // wcat [768][256]
        int o = idx >> 8, c = idx & 255;
        float v = (o < 256) ? wq[o * 256 + c]
                : (o < 512) ? wk[(o - 256) * 256 + c]
                            : wv[(o - 512) * 256 + c];
        wcat[idx] = f2bf(v);
    } else if (idx < 262144) {          // wp [256][256]
        wpb[idx - 196608] = f2bf(wp[idx - 196608]);
    } else if (idx < 262912) {          // bias concat [768]
        int i = idx - 262144;
        biasc[i] = (i < 256) ? bq[i] : (i < 512) ? bk[i - 256] : bv[i - 512];
    }
}

// ---------------- LayerNorm over C, single-pass ----------------
__global__ __launch_bounds__(512) void ln_kernel(const float* __restrict__ x,
                                                 const float* __restrict__ lw,
                                                 const float* __restrict__ lb,
                                                 u16* __restrict__ hn) {
    int tid = threadIdx.x;
    int tl = tid & 63, cg = tid >> 6;
    int tok = blockIdx.x * 64 + tl;
    int b = tok >> 10, n = tok & 1023;
    const float* xb = x + (size_t)b * 262144 + n;     // stride 1024 over c
    int ch0 = cg * 32;
    float v[32];
    float s = 0.f, s2 = 0.f;
    #pragma unroll
    for (int j = 0; j < 32; j++) {
        v[j] = xb[(size_t)(ch0 + j) * 1024];
        s += v[j]; s2 += v[j] * v[j];
    }
    __shared__ float2 red[8][64];
    red[cg][tl] = make_float2(s, s2);
    __syncthreads();
    s = 0.f; s2 = 0.f;
    #pragma unroll
    for (int g = 0; g < 8; g++) { float2 p = red[g][tl]; s += p.x; s2 += p.y; }
    float mean = s * 0.00390625f;
    float var  = s2 * 0.00390625f - mean * mean;
    float rstd = rsqrtf(var + 1e-6f);
    u16* hr = hn + (size_t)tok * 256 + ch0;
    #pragma unroll
    for (int j8 = 0; j8 < 4; j8++) {
        bf8_t pk;
        #pragma unroll
        for (int j = 0; j < 8; j++) {
            int c = j8 * 8 + j;
            float y = (v[c] - mean) * rstd * lw[ch0 + c] + lb[ch0 + c];
            pk[j] = (short)f2bf(y);
        }
        *(bf8_t*)&hr[j8 * 8] = pk;
    }
}

// ---------------- generic B^T bf16 GEMM, 128x128 tile, m97 structure ----------------
// EPI 0 = QKV: writes Q (scaled, [tok][256]) / K (kt[b][c>>3][n][8]) / V (vt3[b][n>>3][c][8])
// EPI 3 = PROJ: +bias +residual, f32 out
template <int EPI>
__global__ __launch_bounds__(256, 2) void gemm_bt(
    const u16* __restrict__ A, const u16* __restrict__ B, void* __restrict__ Cp,
    int lda, int ldb, int ldc, int nk,
    long sA, long sB, long sC,
    const float* __restrict__ aux1, const float* __restrict__ aux2,
    u16* __restrict__ ktp, u16* __restrict__ vtp) {
    __shared__ u16 lsA[128 * 32];
    __shared__ u16 lsB[128 * 32];
    const int tid = threadIdx.x;
    const int z = blockIdx.z;
    const int m0 = blockIdx.x * 128, n0 = blockIdx.y * 128;
    const int lane = tid & 63;
    const int w = tid >> 6, wm = w >> 1, wn = w & 1;
    const int lm = lane & 15, lg = lane >> 4;
    const int sr = tid >> 2, sc = (tid & 3) * 8;

    const u16* ga = A + (size_t)z * sA + (size_t)(m0 + sr) * lda + sc;
    const u16* gb = B + (size_t)z * sB + (size_t)(n0 + sr) * ldb + sc;
    u16* la  = &lsA[sr * 32 + sc];
    u16* lb2 = &lsB[sr * 32 + sc];

    f4_t acc[4][4];
    #pragma unroll
    for (int i = 0; i < 4; i++)
        #pragma unroll
        for (int j = 0; j < 4; j++) acc[i][j] = (f4_t)0.0f;

    for (int kt = 0; kt < nk; ++kt) {
        GLOAD16(ga, la);
        GLOAD16(ga + (size_t)64 * lda, la + 64 * 32);
        GLOAD16(gb, lb2);
        GLOAD16(gb + (size_t)64 * ldb, lb2 + 64 * 32);
        ga += 32; gb += 32;
        __syncthreads();
        bf8_t af[4], bfv[4];
        #pragma unroll
        for (int i = 0; i < 4; i++)
            af[i] = *(const bf8_t*)&lsA[(wm * 64 + i * 16 + lm) * 32 + lg * 8];
        #pragma unroll
        for (int i = 0; i < 4; i++)
            bfv[i] = *(const bf8_t*)&lsB[(wn * 64 + i * 16 + lm) * 32 + lg * 8];
        #pragma unroll
        for (int i = 0; i < 4; i++)
            #pragma unroll
            for (int j = 0; j < 4; j++)
                acc[i][j] = __builtin_amdgcn_mfma_f32_16x16x32_bf16(af[i], bfv[j], acc[i][j], 0, 0, 0);
        __syncthreads();
    }

    const int rb = m0 + wm * 64 + lg * 4;
    const int cb = n0 + wn * 64 + lm;
    #pragma unroll
    for (int i = 0; i < 4; i++)
        #pragma unroll
        for (int j = 0; j < 4; j++)
            #pragma unroll
            for (int r = 0; r < 4; r++) {
                int row = rb + i * 16 + r;
                int col = cb + j * 16;
                float v = acc[i][j][r];
                if (EPI == 0) {
                    float val = v + aux1[col];
                    int bb = row >> 10, n = row & 1023;
                    if (col < 256) {            // Q, pre-scaled
                        ((u16*)Cp)[(size_t)row * 256 + col] = f2bf(val * 0.0625f);
                    } else if (col < 512) {     // K -> kt[b][c>>3][n][8]
                        int c = col - 256;
                        ktp[(((size_t)bb * 32 + (c >> 3)) * 1024 + n) * 8 + (c & 7)] = f2bf(val);
                    } else {                    // V -> vt3[b][n>>3][c][8]
                        int d = col - 512;
                        vtp[(((size_t)bb * 128 + (n >> 3)) * 256 + d) * 8 + (n & 7)] = f2bf(val);
                    }
                } else {
                    size_t idx = (size_t)z * sC + (size_t)row * ldc + col;
                    ((float*)Cp)[idx] = v + aux1[row] + aux2[idx];
                }
            }
}

// ---------------- flash attention, swapped-operand 32x32 MFMA ----------------
// grid 512 = (b, qb32) XCD-swizzled; 256 threads = 4 waves = (dw 2) x (g 2).
// K: direct L2->reg (coalesced via kt layout), prefetched 1 tile ahead - no LDS,
// no barrier dependency. V: LDS double-buffer (conflict-free [kc][d] layout).
// 2 blocks/CU; barrier couples only 4 waves.
__global__ __launch_bounds__(256, 2)
void flash_kernel(const u16* __restrict__ qbuf,
                  const u16* __restrict__ kt,
                  const u16* __restrict__ vt3,
                  u16* __restrict__ O) {
    __shared__ u16 V_lds[2][2][4 * 256 * 8];   // [g][buf][kc][d] 16B units, 64 KB
    __shared__ float mstat[32], lstat[32];

    const int flat = blockIdx.x;
    const int xcd = flat & 7, idx = flat >> 3;
    const int b = (xcd << 1) | (idx & 1);     // 2 batches per XCD -> KV fits L2
    const int qb = idx >> 1;                  // 0..31, 32-row q tile
    const int tid = threadIdx.x;
    const int wv = tid >> 6, lane = tid & 63;
    const int hi = lane >> 5, lq = lane & 31;
    const int dw = wv & 1, g = wv >> 1;

    // Q B-fragments: col=q=lq, chunk tc covers c = tc*16 + hi*8 + e
    const int qrow = qb * 32 + lq;
    const u16* qptr = qbuf + (size_t)(b * 1024 + qrow) * 256 + hi * 8;
    bf8_t qf[16];
    #pragma unroll
    for (int tc = 0; tc < 16; tc++) qf[tc] = *(const bf8_t*)(qptr + tc * 16);

    // K A-fragments direct from L2: row=kv=lq, chunk tc*2+hi; coalesced in lq
    const u16* kp = kt + ((size_t)(b * 32 + hi) * 1024 + g * 512 + lq) * 8;
    bf8_t kreg[16];
    #pragma unroll
    for (int tc = 0; tc < 16; tc++) kreg[tc] = *(const bf8_t*)(kp + tc * 16384);
    kp += 256;   // next 32-kv tile

    float m_r = -1e30f, l_r = 0.f;
    f16x_t o_acc[4];
    #pragma unroll
    for (int dt = 0; dt < 4; dt++) o_acc[dt] = (f16x_t)0.0f;

    // V stage: cid -> (kc = cid>>8, d = cid&255); src vt3 contiguous
#define STAGEV(T, BUF)                                                                    \
    {                                                                                     \
        _Pragma("unroll")                                                                 \
        for (int g2 = 0; g2 < 2; g2++) {                                                  \
            _Pragma("unroll")                                                             \
            for (int it = 0; it < 4; ++it) {                                              \
                int cid = it * 256 + tid;                                                 \
                int kc = cid >> 8, d = cid & 255;                                         \
                const u16* gv = vt3 + (((size_t)b * 128 + g2 * 64 + (T) * 4 + kc) * 256   \
                                       + d) * 8;                                          \
                GLOAD16(gv, &V_lds[g2][BUF][cid * 8]);                                    \
            }                                                                             \
        }                                                                                 \
    }

    STAGEV(0, 0);
    __syncthreads();

    for (int t = 0; t < 16; ++t) {
        const int buf = t & 1;
        if (t < 15) STAGEV(t + 1, buf ^ 1);

        // ---- QK^T: S^T[32kv][32q] = sum_c K[kv][c] Q[q][c], K from registers ----
        f16x_t s0 = (f16x_t)0.0f, s1 = (f16x_t)0.0f;
        __builtin_amdgcn_s_setprio(1);
        #pragma unroll
        for (int tc = 0; tc < 8; tc++) {
            s0 = __builtin_amdgcn_mfma_f32_32x32x16_bf16(kreg[2 * tc],     qf[2 * tc],     s0, 0, 0, 0);
            s1 = __builtin_amdgcn_mfma_f32_32x32x16_bf16(kreg[2 * tc + 1], qf[2 * tc + 1], s1, 0, 0, 0);
        }
        __builtin_amdgcn_s_setprio(0);

        // prefetch next K tile (coalesced L2 loads; latency hides under sm+PV)
        if (t < 15) {
            #pragma unroll
            for (int tc = 0; tc < 16; tc++) kreg[tc] = *(const bf8_t*)(kp + tc * 16384);
            kp += 256;
        }

        f16x_t s = s0 + s1;

        // ---- lane-local online softmax (lane's q = lq; kv split across hi) ----
        float m01 = fmaxf(s[0], s[1]),   m23 = fmaxf(s[2], s[3]);
        float m45 = fmaxf(s[4], s[5]),   m67 = fmaxf(s[6], s[7]);
        float m89 = fmaxf(s[8], s[9]),   mab = fmaxf(s[10], s[11]);
        float mcd = fmaxf(s[12], s[13]), mef = fmaxf(s[14], s[15]);
        float pm = fmaxf(fmaxf(fmaxf(m01, m23), fmaxf(m45, m67)),
                         fmaxf(fmaxf(m89, mab), fmaxf(mcd, mef)));
        float tm = fmaxf(pm, __shfl_xor(pm, 32));
        if (__ballot(tm > m_r + 8.0f)) {          // defer-max THR=8 (T13)
            float mn = fmaxf(m_r, tm);
            float corr = __expf(m_r - mn);
            m_r = mn; l_r *= corr;
            #pragma unroll
            for (int dt = 0; dt < 4; dt++)
                #pragma unroll
                for (int r = 0; r < 16; r++) o_acc[dt][r] *= corr;
        }
        float sum = 0.f;
        #pragma unroll
        for (int r = 0; r < 16; r++) { s[r] = __expf(s[r] - m_r); sum += s[r]; }
        l_r += sum;

        // ---- pack P^T B-fragments: position (hi,e) of chunk c2 holds kv=c2*16+hi*8+e
        // own regs: kv(r) = (r&3) + 8*(r>>2) + 4*hi
        unsigned pw[8];
        #pragma unroll
        for (int j = 0; j < 8; j++) pw[j] = cvt_pk_bf16(s[2 * j], s[2 * j + 1]);
        unsigned px[8];
        #pragma unroll
        for (int j = 0; j < 8; j++) px[j] = __shfl_xor((int)pw[j], 32);
        union { unsigned w[4]; bf8_t v; } f0, f1;
        if (hi == 0) {
            f0.w[0] = pw[0]; f0.w[1] = pw[1]; f0.w[2] = px[0]; f0.w[3] = px[1];
            f1.w[0] = pw[4]; f1.w[1] = pw[5]; f1.w[2] = px[4]; f1.w[3] = px[5];
        } else {
            f0.w[0] = px[2]; f0.w[1] = px[3]; f0.w[2] = pw[2]; f0.w[3] = pw[3];
            f1.w[0] = px[6]; f1.w[1] = px[7]; f1.w[2] = pw[6]; f1.w[3] = pw[7];
        }

        // ---- PV: O^T[d][q] += V^T[d][kv] P^T[kv][q], V fragments batched ----
        const u16* vb = &V_lds[g][buf][0];
        bf8_t vf[8];
        #pragma unroll
        for (int dt = 0; dt < 4; dt++) {
            int vrow = dw * 128 + dt * 32 + lq;
            vf[2 * dt]     = *(const bf8_t*)(vb + (hi * 256 + vrow) * 8);
            vf[2 * dt + 1] = *(const bf8_t*)(vb + ((2 + hi) * 256 + vrow) * 8);
        }
        __builtin_amdgcn_s_setprio(1);
        #pragma unroll
        for (int dt = 0; dt < 4; dt++) {
            o_acc[dt] = __builtin_amdgcn_mfma_f32_32x32x16_bf16(vf[2 * dt],     f0.v, o_acc[dt], 0, 0, 0);
            o_acc[dt] = __builtin_amdgcn_mfma_f32_32x32x16_bf16(vf[2 * dt + 1], f1.v, o_acc[dt], 0, 0, 0);
        }
        __builtin_amdgcn_s_setprio(0);
        __syncthreads();   // prefetch landed + all waves done with buf
    }

    // ---- merge kv-group partials, normalize, write O[tok][c] ----
    float l_tot = l_r + __shfl_xor(l_r, 32);
    float* obuf = (float*)&V_lds[0][0][0];               // 2 x 4096 f32 = 32 KB
    float* rb = obuf + dw * 4096;
    if (g == 1) {
        #pragma unroll
        for (int dt = 0; dt < 4; dt++)
            #pragma unroll
            for (int r = 0; r < 16; r++) {
                int drow = dt * 32 + (r & 3) + 8 * (r >> 2) + 4 * hi;
                rb[drow * 32 + lq] = o_acc[dt][r];
            }
        if (dw == 0 && hi == 0) { mstat[lq] = m_r; lstat[lq] = l_tot; }
    }
    __syncthreads();
    if (g == 0) {
        float m1 = mstat[lq], l1 = lstat[lq];
        float mm = fmaxf(m_r, m1);
        float a0 = __expf(m_r - mm), a1 = __expf(m1 - mm);
        float inv = 1.0f / (a0 * l_tot + a1 * l1);
        u16* bounce = (u16*)((char*)&V_lds[0][0][0] + 32768) + dw * (32 * 136);
        #pragma unroll
        for (int dt = 0; dt < 4; dt++)
            #pragma unroll
            for (int r = 0; r < 16; r++) {
                int drow = dt * 32 + (r & 3) + 8 * (r >> 2) + 4 * hi;
                float val = (a0 * o_acc[dt][r] + a1 * rb[drow * 32 + lq]) * inv;
                bounce[lq * 136 + drow] = f2bf(val);
            }
        asm volatile("s_waitcnt lgkmcnt(0)" ::: "memory");
        #pragma unroll
        for (int it = 0; it < 4; it++) {
            int qloc = it * 8 + (lane >> 3);
            int dch = (lane & 7) * 16;
            bf8_t lo8 = *(const bf8_t*)&bounce[qloc * 136 + dch];
            bf8_t hi8 = *(const bf8_t*)&bounce[qloc * 136 + dch + 8];
            u16* dst = O + (size_t)(b * 1024 + qb * 32 + qloc) * 256 + dw * 128 + dch;
            *(bf8_t*)dst = lo8;
            *(bf8_t*)(dst + 8) = hi8;
        }
    }
#undef STAGEV
}

extern "C" void kernel_launch(void* const* d_in, const int* in_sizes, int n_in,
                              void* d_out, int out_size, void* d_ws, size_t ws_size,
                              hipStream_t stream) {
    (void)in_sizes; (void)n_in; (void)out_size; (void)ws_size;
    const float* x   = (const float*)d_in[0];
    const float* lnw = (const float*)d_in[1];
    const float* lnb = (const float*)d_in[2];
    const float* wq  = (const float*)d_in[3];
    const float* bq  = (const float*)d_in[4];
    const float* wk  = (const float*)d_in[5];
    const float* bk  = (const float*)d_in[6];
    const float* wv  = (const float*)d_in[7];
    const float* bv  = (const float*)d_in[8];
    const float* wp  = (const float*)d_in[9];
    const float* bp  = (const float*)d_in[10];
    float* out = (float*)d_out;

    char* ws = (char*)d_ws;
    u16*   wcat  = (u16*)(ws);              // 768*256 bf16
    u16*   wpb   = (u16*)(ws + 0x60000);    // 256*256 bf16
    float* biasc = (float*)(ws + 0x80000);  // 768 f32
    u16*   hn    = (u16*)(ws + 0x90000);    // 16384*256 bf16   (8MB)
    u16*   qbuf  = (u16*)(ws + 0x890000);   // 16384*256 bf16   (8MB)
    u16*   kt    = (u16*)(ws + 0x1090000);  // [16][32][1024][8] bf16 (8MB)
    u16*   vt3   = (u16*)(ws + 0x1890000);  // [16][128][256][8] bf16 (8MB)
    u16*   O     = (u16*)(ws + 0x2090000);  // 16384*256 bf16   (8MB)

    prep_kernel<<<1028, 256, 0, stream>>>(wq, wk, wv, wp, bq, bk, bv, wcat, wpb, biasc);
    ln_kernel<<<256, 512, 0, stream>>>(x, lnw, lnb, hn);
    // QKV: [16384,768] = hn x wcat^T; epilogue routes Q/K/V into qbuf/kt/vt3
    gemm_bt<0><<<dim3(128, 6, 1), 256, 0, stream>>>(hn, wcat, qbuf, 256, 256, 768, 8,
                                                    0, 0, 0, biasc, nullptr, kt, vt3);
    // fused attention (K L2->reg prefetch, V LDS dbuf, 2 blocks/CU)
    flash_kernel<<<512, 256, 0, stream>>>(qbuf, kt, vt3, O);
    // out[b] = wp x O[b]^T + bp + x  (f32)
    gemm_bt<3><<<dim3(2, 8, 16), 256, 0, stream>>>(wpb, O, out, 256, 256, 1024, 8,
                                                   0, 262144, 262144, bp, x,
                                                   nullptr, nullptr);
}

// Round 9
// 82.985 us; speedup vs baseline: 1.1179x; 1.1179x over previous
//
#include <hip/hip_runtime.h>
#include <hip/hip_bf16.h>
#include <stdint.h>

typedef __attribute__((ext_vector_type(8))) short bf8_t;    // 8 bf16 in 4 VGPRs
typedef __attribute__((ext_vector_type(4))) short s4_t;
typedef __attribute__((ext_vector_type(4))) float f4_t;
typedef __attribute__((ext_vector_type(16))) float f16x_t;  // 32x32 mfma acc
typedef unsigned short u16;

#define GLOAD16(g, l) __builtin_amdgcn_global_load_lds(                                  \
    (const __attribute__((address_space(1))) void*)(g),                                  \
    (__attribute__((address_space(3))) void*)(l), 16, 0, 0)

__device__ __forceinline__ u16 f2bf(float f) {
    union { float f; unsigned u; } c; c.f = f;
    unsigned u = c.u;
    return (u16)((u + 0x7fffu + ((u >> 16) & 1u)) >> 16);   // RNE, inputs finite
}

__device__ __forceinline__ unsigned cvt_pk_bf16(float lo, float hi_) {
    unsigned r;
    asm("v_cvt_pk_bf16_f32 %0, %1, %2" : "=v"(r) : "v"(lo), "v"(hi_));
    return r;                                                // lo -> bits[15:0]
}

// ---------------- weights -> bf16 ----------------
__global__ void prep_kernel(const float* __restrict__ wq, const float* __restrict__ wk,
                            const float* __restrict__ wv, const float* __restrict__ wp,
                            const float* __restrict__ bq, const float* __restrict__ bk,
                            const float* __restrict__ bv,
                            u16* __restrict__ wcat, u16* __restrict__ wpb,
                            float* __restrict__ biasc) {
    int idx = blockIdx.x * 256 + threadIdx.x;
    if (idx < 196608) {                 // wcat [768][256]
        int o = idx >> 8, c = idx & 255;
        float v = (o < 256) ? wq[o * 256 + c]
                : (o < 512) ? wk[(o - 256) * 256 + c]
                            : wv[(o - 512) * 256 + c];
        wcat[idx] = f2bf(v);
    } else if (idx < 262144) {          // wp [256][256]
        wpb[idx - 196608] = f2bf(wp[idx - 196608]);
    } else if (idx < 262912) {          // bias concat [768]
        int i = idx - 262144;
        biasc[i] = (i < 256) ? bq[i] : (i < 512) ? bk[i - 256] : bv[i - 512];
    }
}

// ---------------- LayerNorm over C, single-pass ----------------
__global__ __launch_bounds__(512) void ln_kernel(const float* __restrict__ x,
                                                 const float* __restrict__ lw,
                                                 const float* __restrict__ lb,
                                                 u16* __restrict__ hn) {
    int tid = threadIdx.x;
    int tl = tid & 63, cg = tid >> 6;
    int tok = blockIdx.x * 64 + tl;
    int b = tok >> 10, n = tok & 1023;
    const float* xb = x + (size_t)b * 262144 + n;     // stride 1024 over c
    int ch0 = cg * 32;
    float v[32];
    float s = 0.f, s2 = 0.f;
    #pragma unroll
    for (int j = 0; j < 32; j++) {
        v[j] = xb[(size_t)(ch0 + j) * 1024];
        s += v[j]; s2 += v[j] * v[j];
    }
    __shared__ float2 red[8][64];
    red[cg][tl] = make_float2(s, s2);
    __syncthreads();
    s = 0.f; s2 = 0.f;
    #pragma unroll
    for (int g = 0; g < 8; g++) { float2 p = red[g][tl]; s += p.x; s2 += p.y; }
    float mean = s * 0.00390625f;
    float var  = s2 * 0.00390625f - mean * mean;
    float rstd = rsqrtf(var + 1e-6f);
    u16* hr = hn + (size_t)tok * 256 + ch0;
    #pragma unroll
    for (int j8 = 0; j8 < 4; j8++) {
        bf8_t pk;
        #pragma unroll
        for (int j = 0; j < 8; j++) {
            int c = j8 * 8 + j;
            float y = (v[c] - mean) * rstd * lw[ch0 + c] + lb[ch0 + c];
            pk[j] = (short)f2bf(y);
        }
        *(bf8_t*)&hr[j8 * 8] = pk;
    }
}

// ---------------- generic B^T bf16 GEMM, 128x128 tile, m97 structure ----------------
// EPI 0 = QKV: writes Q (scaled, [tok][256]) / K (kt[b][c>>3][n][8]) / V (vt3[b][n>>3][c][8])
// EPI 3 = PROJ: +bias +residual, f32 out
template <int EPI>
__global__ __launch_bounds__(256, 2) void gemm_bt(
    const u16* __restrict__ A, const u16* __restrict__ B, void* __restrict__ Cp,
    int lda, int ldb, int ldc, int nk,
    long sA, long sB, long sC,
    const float* __restrict__ aux1, const float* __restrict__ aux2,
    u16* __restrict__ ktp, u16* __restrict__ vtp) {
    __shared__ u16 lsA[128 * 32];
    __shared__ u16 lsB[128 * 32];
    const int tid = threadIdx.x;
    const int z = blockIdx.z;
    const int m0 = blockIdx.x * 128, n0 = blockIdx.y * 128;
    const int lane = tid & 63;
    const int w = tid >> 6, wm = w >> 1, wn = w & 1;
    const int lm = lane & 15, lg = lane >> 4;
    const int sr = tid >> 2, sc = (tid & 3) * 8;

    const u16* ga = A + (size_t)z * sA + (size_t)(m0 + sr) * lda + sc;
    const u16* gb = B + (size_t)z * sB + (size_t)(n0 + sr) * ldb + sc;
    u16* la  = &lsA[sr * 32 + sc];
    u16* lb2 = &lsB[sr * 32 + sc];

    f4_t acc[4][4];
    #pragma unroll
    for (int i = 0; i < 4; i++)
        #pragma unroll
        for (int j = 0; j < 4; j++) acc[i][j] = (f4_t)0.0f;

    for (int kt = 0; kt < nk; ++kt) {
        GLOAD16(ga, la);
        GLOAD16(ga + (size_t)64 * lda, la + 64 * 32);
        GLOAD16(gb, lb2);
        GLOAD16(gb + (size_t)64 * ldb, lb2 + 64 * 32);
        ga += 32; gb += 32;
        __syncthreads();
        bf8_t af[4], bfv[4];
        #pragma unroll
        for (int i = 0; i < 4; i++)
            af[i] = *(const bf8_t*)&lsA[(wm * 64 + i * 16 + lm) * 32 + lg * 8];
        #pragma unroll
        for (int i = 0; i < 4; i++)
            bfv[i] = *(const bf8_t*)&lsB[(wn * 64 + i * 16 + lm) * 32 + lg * 8];
        #pragma unroll
        for (int i = 0; i < 4; i++)
            #pragma unroll
            for (int j = 0; j < 4; j++)
                acc[i][j] = __builtin_amdgcn_mfma_f32_16x16x32_bf16(af[i], bfv[j], acc[i][j], 0, 0, 0);
        __syncthreads();
    }

    const int rb = m0 + wm * 64 + lg * 4;
    const int cb = n0 + wn * 64 + lm;
    #pragma unroll
    for (int i = 0; i < 4; i++)
        #pragma unroll
        for (int j = 0; j < 4; j++)
            #pragma unroll
            for (int r = 0; r < 4; r++) {
                int row = rb + i * 16 + r;
                int col = cb + j * 16;
                float v = acc[i][j][r];
                if (EPI == 0) {
                    float val = v + aux1[col];
                    int bb = row >> 10, n = row & 1023;
                    if (col < 256) {            // Q, pre-scaled
                        ((u16*)Cp)[(size_t)row * 256 + col] = f2bf(val * 0.0625f);
                    } else if (col < 512) {     // K -> kt[b][c>>3][n][8]
                        int c = col - 256;
                        ktp[(((size_t)bb * 32 + (c >> 3)) * 1024 + n) * 8 + (c & 7)] = f2bf(val);
                    } else {                    // V -> vt3[b][n>>3][c][8]
                        int d = col - 512;
                        vtp[(((size_t)bb * 128 + (n >> 3)) * 256 + d) * 8 + (n & 7)] = f2bf(val);
                    }
                } else {
                    size_t idx = (size_t)z * sC + (size_t)row * ldc + col;
                    ((float*)Cp)[idx] = v + aux1[row] + aux2[idx];
                }
            }
}

// ---------------- flash attention, swapped-operand 32x32 MFMA ----------------
// grid 256 = (b, qb) XCD-swizzled; 512 threads = 8 waves = (qw 2) x (dw 2) x (g 2).
// Counted-vmcnt pipeline (T3/T4): stage 2 tiles ahead; barriers wait lgkm /
// vmcnt(8) only -- NEVER vmcnt(0) in the steady-state loop.
__global__ __launch_bounds__(512)
__attribute__((amdgpu_waves_per_eu(2, 2)))
void flash_kernel(const u16* __restrict__ qbuf,
                  const u16* __restrict__ kt,
                  const u16* __restrict__ vt3,
                  u16* __restrict__ O) {
    __shared__ u16 K_lds[2][2][32 * 32 * 8];   // [g][buf][chunk][kv] 16B units, 64 KB
    __shared__ u16 V_lds[2][2][4 * 256 * 8];   // [g][buf][kc][d]    16B units, 64 KB
    __shared__ float mstat[2][32], lstat[2][32];

    const int flat = blockIdx.x;
    const int xcd = flat & 7, idx = flat >> 3;
    const int b = (xcd << 1) | (idx & 1);     // 2 batches per XCD -> KV fits L2
    const int qb = idx >> 1;
    const int tid = threadIdx.x;
    const int wv = tid >> 6, lane = tid & 63;
    const int hi = lane >> 5, lq = lane & 31;
    const int qw = wv & 1, dw = (wv >> 1) & 1, g = wv >> 2;

    // Q B-fragments: col=q=lq, chunk tc covers c = tc*16 + hi*8 + e
    const int qrow = qb * 64 + qw * 32 + lq;
    const u16* qptr = qbuf + (size_t)(b * 1024 + qrow) * 256 + hi * 8;
    bf8_t qf[16];
    #pragma unroll
    for (int tc = 0; tc < 16; tc++) qf[tc] = *(const bf8_t*)(qptr + tc * 16);

    float m_r = -1e30f, l_r = 0.f;
    f16x_t o_acc[4];
    #pragma unroll
    for (int dt = 0; dt < 4; dt++) o_acc[dt] = (f16x_t)0.0f;

    // K stage: cid -> (chunk = cid>>5, kvl = cid&31); src kt contiguous 512B runs
    // V stage: cid -> (kc = cid>>8, d = cid&255);     src vt3 contiguous 1KB runs
    // 8 GLOAD16 per thread per STAGE.
#define STAGE(T, BUF)                                                                     \
    {                                                                                     \
        _Pragma("unroll")                                                                 \
        for (int g2 = 0; g2 < 2; g2++) {                                                  \
            _Pragma("unroll")                                                             \
            for (int it = 0; it < 2; it++) {                                              \
                int cid = it * 512 + tid;                                                 \
                int chunk = cid >> 5, kvl = cid & 31;                                     \
                const u16* gk = kt + (((size_t)b * 32 + chunk) * 1024                     \
                                      + g2 * 512 + (T) * 32 + kvl) * 8;                   \
                GLOAD16(gk, &K_lds[g2][BUF][cid * 8]);                                    \
            }                                                                             \
            _Pragma("unroll")                                                             \
            for (int it = 0; it < 2; it++) {                                              \
                int cid = it * 512 + tid;                                                 \
                int kc = cid >> 8, d = cid & 255;                                         \
                const u16* gv = vt3 + (((size_t)b * 128 + g2 * 64 + (T) * 4 + kc) * 256   \
                                       + d) * 8;                                          \
                GLOAD16(gv, &V_lds[g2][BUF][cid * 8]);                                    \
            }                                                                             \
        }                                                                                 \
    }

    // prologue: 2-deep prefetch; drain stage(0) (leave stage(1) in flight)
    STAGE(0, 0);
    STAGE(1, 1);
    asm volatile("s_waitcnt vmcnt(8)" ::: "memory");
    __builtin_amdgcn_s_barrier();

    for (int t = 0; t < 16; ++t) {
        const int buf = t & 1;

        // ---- batched K fragment reads (buf is safe: B2 of prev tile) ----
        const u16* kb = &K_lds[g][buf][0];
        bf8_t kf[16];
        #pragma unroll
        for (int tc = 0; tc < 16; tc++)
            kf[tc] = *(const bf8_t*)(kb + ((tc * 2 + hi) * 32 + lq) * 8);

        // ---- QK^T: S^T[32kv][32q] ----
        f16x_t s0 = (f16x_t)0.0f, s1 = (f16x_t)0.0f;
        __builtin_amdgcn_s_setprio(1);
        #pragma unroll
        for (int tc = 0; tc < 8; tc++) {
            s0 = __builtin_amdgcn_mfma_f32_32x32x16_bf16(kf[2 * tc],     qf[2 * tc],     s0, 0, 0, 0);
            s1 = __builtin_amdgcn_mfma_f32_32x32x16_bf16(kf[2 * tc + 1], qf[2 * tc + 1], s1, 0, 0, 0);
        }
        __builtin_amdgcn_s_setprio(0);

        // ---- batched V fragment reads (latency hides under softmax) ----
        const u16* vb = &V_lds[g][buf][0];
        bf8_t vf[8];
        #pragma unroll
        for (int dt = 0; dt < 4; dt++) {
            int vrow = dw * 128 + dt * 32 + lq;
            vf[2 * dt]     = *(const bf8_t*)(vb + (hi * 256 + vrow) * 8);
            vf[2 * dt + 1] = *(const bf8_t*)(vb + ((2 + hi) * 256 + vrow) * 8);
        }

        f16x_t s = s0 + s1;

        // ---- lane-local online softmax (lane's q = lq; kv split across hi) ----
        float m01 = fmaxf(s[0], s[1]),   m23 = fmaxf(s[2], s[3]);
        float m45 = fmaxf(s[4], s[5]),   m67 = fmaxf(s[6], s[7]);
        float m89 = fmaxf(s[8], s[9]),   mab = fmaxf(s[10], s[11]);
        float mcd = fmaxf(s[12], s[13]), mef = fmaxf(s[14], s[15]);
        float pm = fmaxf(fmaxf(fmaxf(m01, m23), fmaxf(m45, m67)),
                         fmaxf(fmaxf(m89, mab), fmaxf(mcd, mef)));
        float tm = fmaxf(pm, __shfl_xor(pm, 32));
        if (__ballot(tm > m_r + 8.0f)) {          // defer-max THR=8 (T13)
            float mn = fmaxf(m_r, tm);
            float corr = __expf(m_r - mn);
            m_r = mn; l_r *= corr;
            #pragma unroll
            for (int dt = 0; dt < 4; dt++)
                #pragma unroll
                for (int r = 0; r < 16; r++) o_acc[dt][r] *= corr;
        }
        float sum = 0.f;
        #pragma unroll
        for (int r = 0; r < 16; r++) { s[r] = __expf(s[r] - m_r); sum += s[r]; }
        l_r += sum;

        // ---- pack P^T B-fragments ----
        unsigned pw[8];
        #pragma unroll
        for (int j = 0; j < 8; j++) pw[j] = cvt_pk_bf16(s[2 * j], s[2 * j + 1]);
        unsigned px[8];
        #pragma unroll
        for (int j = 0; j < 8; j++) px[j] = __shfl_xor((int)pw[j], 32);
        union { unsigned w[4]; bf8_t v; } f0, f1;
        if (hi == 0) {
            f0.w[0] = pw[0]; f0.w[1] = pw[1]; f0.w[2] = px[0]; f0.w[3] = px[1];
            f1.w[0] = pw[4]; f1.w[1] = pw[5]; f1.w[2] = px[4]; f1.w[3] = px[5];
        } else {
            f0.w[0] = px[2]; f0.w[1] = px[3]; f0.w[2] = pw[2]; f0.w[3] = pw[3];
            f1.w[0] = px[6]; f1.w[1] = px[7]; f1.w[2] = pw[6]; f1.w[3] = pw[7];
        }

        // ---- B1: all our LDS reads of buf complete -> safe to overwrite ----
        asm volatile("s_waitcnt lgkmcnt(0)" ::: "memory");
        __builtin_amdgcn_s_barrier();
        if (t < 14) STAGE(t + 2, buf);

        // ---- PV: O^T[d][q] += V^T[d][kv] P^T[kv][q] (all operands in regs) ----
        __builtin_amdgcn_s_setprio(1);
        #pragma unroll
        for (int dt = 0; dt < 4; dt++) {
            o_acc[dt] = __builtin_amdgcn_mfma_f32_32x32x16_bf16(vf[2 * dt],     f0.v, o_acc[dt], 0, 0, 0);
            o_acc[dt] = __builtin_amdgcn_mfma_f32_32x32x16_bf16(vf[2 * dt + 1], f1.v, o_acc[dt], 0, 0, 0);
        }
        __builtin_amdgcn_s_setprio(0);

        // ---- B2: stage(t+1) landed in every wave -> next tile may read ----
        if (t < 15) {
            if (t < 14) { asm volatile("s_waitcnt vmcnt(8)" ::: "memory"); }
            else        { asm volatile("s_waitcnt vmcnt(0)" ::: "memory"); }
            __builtin_amdgcn_s_barrier();
        }
    }

    __syncthreads();   // all waves out of the loop before LDS reuse

    // ---- merge kv-group partials, normalize, write O[tok][c] ----
    float l_tot = l_r + __shfl_xor(l_r, 32);
    float* obuf = (float*)&K_lds[0][0][0];               // 4 x 4096 f32 = 64 KB
    float* rb = obuf + (qw * 2 + dw) * 4096;
    if (g == 1) {
        #pragma unroll
        for (int dt = 0; dt < 4; dt++)
            #pragma unroll
            for (int r = 0; r < 16; r++) {
                int drow = dt * 32 + (r & 3) + 8 * (r >> 2) + 4 * hi;
                rb[drow * 32 + lq] = o_acc[dt][r];
            }
        if (dw == 0 && hi == 0) { mstat[qw][lq] = m_r; lstat[qw][lq] = l_tot; }
    }
    __syncthreads();
    if (g == 0) {
        float m1 = mstat[qw][lq], l1 = lstat[qw][lq];
        float mm = fmaxf(m_r, m1);
        float a0 = __expf(m_r - mm), a1 = __expf(m1 - mm);
        float inv = 1.0f / (a0 * l_tot + a1 * l1);
        u16* bounce = (u16*)&V_lds[0][0][0] + (qw * 2 + dw) * (32 * 136);
        #pragma unroll
        for (int dt = 0; dt < 4; dt++)
            #pragma unroll
            for (int r = 0; r < 16; r++) {
                int drow = dt * 32 + (r & 3) + 8 * (r >> 2) + 4 * hi;
                float val = (a0 * o_acc[dt][r] + a1 * rb[drow * 32 + lq]) * inv;
                bounce[lq * 136 + drow] = f2bf(val);
            }
        asm volatile("s_waitcnt lgkmcnt(0)" ::: "memory");
        #pragma unroll
        for (int it = 0; it < 4; it++) {
            int qloc = it * 8 + (lane >> 3);
            int dch = (lane & 7) * 16;
            bf8_t lo8 = *(const bf8_t*)&bounce[qloc * 136 + dch];
            bf8_t hi8 = *(const bf8_t*)&bounce[qloc * 136 + dch + 8];
            u16* dst = O + (size_t)(b * 1024 + qb * 64 + qw * 32 + qloc) * 256 + dw * 128 + dch;
            *(bf8_t*)dst = lo8;
            *(bf8_t*)(dst + 8) = hi8;
        }
    }
#undef STAGE
}

extern "C" void kernel_launch(void* const* d_in, const int* in_sizes, int n_in,
                              void* d_out, int out_size, void* d_ws, size_t ws_size,
                              hipStream_t stream) {
    (void)in_sizes; (void)n_in; (void)out_size; (void)ws_size;
    const float* x   = (const float*)d_in[0];
    const float* lnw = (const float*)d_in[1];
    const float* lnb = (const float*)d_in[2];
    const float* wq  = (const float*)d_in[3];
    const float* bq  = (const float*)d_in[4];
    const float* wk  = (const float*)d_in[5];
    const float* bk  = (const float*)d_in[6];
    const float* wv  = (const float*)d_in[7];
    const float* bv  = (const float*)d_in[8];
    const float* wp  = (const float*)d_in[9];
    const float* bp  = (const float*)d_in[10];
    float* out = (float*)d_out;

    char* ws = (char*)d_ws;
    u16*   wcat  = (u16*)(ws);              // 768*256 bf16
    u16*   wpb   = (u16*)(ws + 0x60000);    // 256*256 bf16
    float* biasc = (float*)(ws + 0x80000);  // 768 f32
    u16*   hn    = (u16*)(ws + 0x90000);    // 16384*256 bf16   (8MB)
    u16*   qbuf  = (u16*)(ws + 0x890000);   // 16384*256 bf16   (8MB)
    u16*   kt    = (u16*)(ws + 0x1090000);  // [16][32][1024][8] bf16 (8MB)
    u16*   vt3   = (u16*)(ws + 0x1890000);  // [16][128][256][8] bf16 (8MB)
    u16*   O     = (u16*)(ws + 0x2090000);  // 16384*256 bf16   (8MB)

    prep_kernel<<<1028, 256, 0, stream>>>(wq, wk, wv, wp, bq, bk, bv, wcat, wpb, biasc);
    ln_kernel<<<256, 512, 0, stream>>>(x, lnw, lnb, hn);
    // QKV: [16384,768] = hn x wcat^T; epilogue routes Q/K/V into qbuf/kt/vt3
    gemm_bt<0><<<dim3(128, 6, 1), 256, 0, stream>>>(hn, wcat, qbuf, 256, 256, 768, 8,
                                                    0, 0, 0, biasc, nullptr, kt, vt3);
    // fused attention (counted-vmcnt 2-deep pipeline)
    flash_kernel<<<256, 512, 0, stream>>>(qbuf, kt, vt3, O);
    // out[b] = wp x O[b]^T + bp + x  (f32)
    gemm_bt<3><<<dim3(2, 8, 16), 256, 0, stream>>>(wpb, O, out, 256, 256, 1024, 8,
                                                   0, 262144, 262144, bp, x,
                                                   nullptr, nullptr);
}

// Round 10
// 75.910 us; speedup vs baseline: 1.2221x; 1.0932x over previous
//
#include <hip/hip_runtime.h>
#include <hip/hip_bf16.h>
#include <stdint.h>

typedef __attribute__((ext_vector_type(8))) short bf8_t;    // 8 bf16 in 4 VGPRs
typedef __attribute__((ext_vector_type(4))) short s4_t;
typedef __attribute__((ext_vector_type(4))) float f4_t;
typedef __attribute__((ext_vector_type(16))) float f16x_t;  // 32x32 mfma acc
typedef unsigned short u16;

#define GLOAD16(g, l) __builtin_amdgcn_global_load_lds(                                  \
    (const __attribute__((address_space(1))) void*)(g),                                  \
    (__attribute__((address_space(3))) void*)(l), 16, 0, 0)

__device__ __forceinline__ u16 f2bf(float f) {
    union { float f; unsigned u; } c; c.f = f;
    unsigned u = c.u;
    return (u16)((u + 0x7fffu + ((u >> 16) & 1u)) >> 16);   // RNE, inputs finite
}

__device__ __forceinline__ unsigned cvt_pk_bf16(float lo, float hi_) {
    unsigned r;
    asm("v_cvt_pk_bf16_f32 %0, %1, %2" : "=v"(r) : "v"(lo), "v"(hi_));
    return r;                                                // lo -> bits[15:0]
}

// ---------------- weights -> bf16 ----------------
// wpt layout: [d>>3][c_out][8] so proj A-fragments are coalesced (like kt)
__global__ void prep_kernel(const float* __restrict__ wq, const float* __restrict__ wk,
                            const float* __restrict__ wv, const float* __restrict__ wp,
                            const float* __restrict__ bq, const float* __restrict__ bk,
                            const float* __restrict__ bv,
                            u16* __restrict__ wcat, u16* __restrict__ wpt,
                            float* __restrict__ biasc) {
    int idx = blockIdx.x * 256 + threadIdx.x;
    if (idx < 196608) {                 // wcat [768][256]
        int o = idx >> 8, c = idx & 255;
        float v = (o < 256) ? wq[o * 256 + c]
                : (o < 512) ? wk[(o - 256) * 256 + c]
                            : wv[(o - 512) * 256 + c];
        wcat[idx] = f2bf(v);
    } else if (idx < 262144) {          // wp[o][d] -> wpt[(d>>3)][o][8]
        int i = idx - 196608;
        int o = i >> 8, d = i & 255;
        wpt[(((d >> 3) * 256) + o) * 8 + (d & 7)] = f2bf(wp[i]);
    } else if (idx < 262912) {          // bias concat [768]
        int i = idx - 262144;
        biasc[i] = (i < 256) ? bq[i] : (i < 512) ? bk[i - 256] : bv[i - 512];
    }
}

// ---------------- LayerNorm over C, single-pass ----------------
__global__ __launch_bounds__(512) void ln_kernel(const float* __restrict__ x,
                                                 const float* __restrict__ lw,
                                                 const float* __restrict__ lb,
                                                 u16* __restrict__ hn) {
    int tid = threadIdx.x;
    int tl = tid & 63, cg = tid >> 6;
    int tok = blockIdx.x * 64 + tl;
    int b = tok >> 10, n = tok & 1023;
    const float* xb = x + (size_t)b * 262144 + n;     // stride 1024 over c
    int ch0 = cg * 32;
    float v[32];
    float s = 0.f, s2 = 0.f;
    #pragma unroll
    for (int j = 0; j < 32; j++) {
        v[j] = xb[(size_t)(ch0 + j) * 1024];
        s += v[j]; s2 += v[j] * v[j];
    }
    __shared__ float2 red[8][64];
    red[cg][tl] = make_float2(s, s2);
    __syncthreads();
    s = 0.f; s2 = 0.f;
    #pragma unroll
    for (int g = 0; g < 8; g++) { float2 p = red[g][tl]; s += p.x; s2 += p.y; }
    float mean = s * 0.00390625f;
    float var  = s2 * 0.00390625f - mean * mean;
    float rstd = rsqrtf(var + 1e-6f);
    u16* hr = hn + (size_t)tok * 256 + ch0;
    #pragma unroll
    for (int j8 = 0; j8 < 4; j8++) {
        bf8_t pk;
        #pragma unroll
        for (int j = 0; j < 8; j++) {
            int c = j8 * 8 + j;
            float y = (v[c] - mean) * rstd * lw[ch0 + c] + lb[ch0 + c];
            pk[j] = (short)f2bf(y);
        }
        *(bf8_t*)&hr[j8 * 8] = pk;
    }
}

// ---------------- QKV B^T bf16 GEMM, 128x128 tile, m97 structure ----------------
// writes Q (scaled, [tok][256]) / K (kt[b][c>>3][n][8]) / V (vt3[b][n>>3][c][8])
__global__ __launch_bounds__(256, 2) void gemm_qkv(
    const u16* __restrict__ A, const u16* __restrict__ B, u16* __restrict__ Cp,
    const float* __restrict__ aux1,
    u16* __restrict__ ktp, u16* __restrict__ vtp) {
    __shared__ u16 lsA[128 * 32];
    __shared__ u16 lsB[128 * 32];
    const int tid = threadIdx.x;
    const int m0 = blockIdx.x * 128, n0 = blockIdx.y * 128;
    const int lane = tid & 63;
    const int w = tid >> 6, wm = w >> 1, wn = w & 1;
    const int lm = lane & 15, lg = lane >> 4;
    const int sr = tid >> 2, sc = (tid & 3) * 8;

    const u16* ga = A + (size_t)(m0 + sr) * 256 + sc;
    const u16* gb = B + (size_t)(n0 + sr) * 256 + sc;
    u16* la  = &lsA[sr * 32 + sc];
    u16* lb2 = &lsB[sr * 32 + sc];

    f4_t acc[4][4];
    #pragma unroll
    for (int i = 0; i < 4; i++)
        #pragma unroll
        for (int j = 0; j < 4; j++) acc[i][j] = (f4_t)0.0f;

    for (int kt = 0; kt < 8; ++kt) {
        GLOAD16(ga, la);
        GLOAD16(ga + (size_t)64 * 256, la + 64 * 32);
        GLOAD16(gb, lb2);
        GLOAD16(gb + (size_t)64 * 256, lb2 + 64 * 32);
        ga += 32; gb += 32;
        __syncthreads();
        bf8_t af[4], bfv[4];
        #pragma unroll
        for (int i = 0; i < 4; i++)
            af[i] = *(const bf8_t*)&lsA[(wm * 64 + i * 16 + lm) * 32 + lg * 8];
        #pragma unroll
        for (int i = 0; i < 4; i++)
            bfv[i] = *(const bf8_t*)&lsB[(wn * 64 + i * 16 + lm) * 32 + lg * 8];
        #pragma unroll
        for (int i = 0; i < 4; i++)
            #pragma unroll
            for (int j = 0; j < 4; j++)
                acc[i][j] = __builtin_amdgcn_mfma_f32_16x16x32_bf16(af[i], bfv[j], acc[i][j], 0, 0, 0);
        __syncthreads();
    }

    const int rb = m0 + wm * 64 + lg * 4;
    const int cb = n0 + wn * 64 + lm;
    #pragma unroll
    for (int i = 0; i < 4; i++)
        #pragma unroll
        for (int j = 0; j < 4; j++)
            #pragma unroll
            for (int r = 0; r < 4; r++) {
                int row = rb + i * 16 + r;
                int col = cb + j * 16;
                float val = acc[i][j][r] + aux1[col];
                int bb = row >> 10, n = row & 1023;
                if (col < 256) {            // Q, pre-scaled
                    Cp[(size_t)row * 256 + col] = f2bf(val * 0.0625f);
                } else if (col < 512) {     // K -> kt[b][c>>3][n][8]
                    int c = col - 256;
                    ktp[(((size_t)bb * 32 + (c >> 3)) * 1024 + n) * 8 + (c & 7)] = f2bf(val);
                } else {                    // V -> vt3[b][n>>3][c][8]
                    int d = col - 512;
                    vtp[(((size_t)bb * 128 + (n >> 3)) * 256 + d) * 8 + (n & 7)] = f2bf(val);
                }
            }
}

// ---------------- flash attention + fused proj ----------------
// grid 256 = (b, qb) XCD-swizzled; 512 threads = 8 waves = (qw 2) x (dw 2) x (g 2).
// Main loop: counted-vmcnt 2-deep pipeline (R9-verified). Epilogue: merge kv
// partials -> O tile (bf16) in LDS -> in-block proj GEMM (wp x O^T + bp + x).
__global__ __launch_bounds__(512)
__attribute__((amdgpu_waves_per_eu(2, 2)))
void flash_kernel(const u16* __restrict__ qbuf,
                  const u16* __restrict__ kt,
                  const u16* __restrict__ vt3,
                  const u16* __restrict__ wpt,
                  const float* __restrict__ bp,
                  const float* __restrict__ x,
                  float* __restrict__ out) {
    __shared__ u16 K_lds[2][2][32 * 32 * 8];   // [g][buf][chunk][kv] 16B units, 64 KB
    __shared__ u16 V_lds[2][2][4 * 256 * 8];   // [g][buf][kc][d]    16B units, 64 KB
    __shared__ float mstat[2][32], lstat[2][32];

    const int flat = blockIdx.x;
    const int xcd = flat & 7, idx = flat >> 3;
    const int b = (xcd << 1) | (idx & 1);     // 2 batches per XCD -> KV fits L2
    const int qb = idx >> 1;
    const int tid = threadIdx.x;
    const int wv = tid >> 6, lane = tid & 63;
    const int hi = lane >> 5, lq = lane & 31;
    const int qw = wv & 1, dw = (wv >> 1) & 1, g = wv >> 2;

    // Q B-fragments: col=q=lq, chunk tc covers c = tc*16 + hi*8 + e
    const int qrow = qb * 64 + qw * 32 + lq;
    const u16* qptr = qbuf + (size_t)(b * 1024 + qrow) * 256 + hi * 8;
    bf8_t qf[16];
    #pragma unroll
    for (int tc = 0; tc < 16; tc++) qf[tc] = *(const bf8_t*)(qptr + tc * 16);

    float m_r = -1e30f, l_r = 0.f;
    f16x_t o_acc[4];
    #pragma unroll
    for (int dt = 0; dt < 4; dt++) o_acc[dt] = (f16x_t)0.0f;

#define STAGE(T, BUF)                                                                     \
    {                                                                                     \
        _Pragma("unroll")                                                                 \
        for (int g2 = 0; g2 < 2; g2++) {                                                  \
            _Pragma("unroll")                                                             \
            for (int it = 0; it < 2; it++) {                                              \
                int cid = it * 512 + tid;                                                 \
                int chunk = cid >> 5, kvl = cid & 31;                                     \
                const u16* gk = kt + (((size_t)b * 32 + chunk) * 1024                     \
                                      + g2 * 512 + (T) * 32 + kvl) * 8;                   \
                GLOAD16(gk, &K_lds[g2][BUF][cid * 8]);                                    \
            }                                                                             \
            _Pragma("unroll")                                                             \
            for (int it = 0; it < 2; it++) {                                              \
                int cid = it * 512 + tid;                                                 \
                int kc = cid >> 8, d = cid & 255;                                         \
                const u16* gv = vt3 + (((size_t)b * 128 + g2 * 64 + (T) * 4 + kc) * 256   \
                                       + d) * 8;                                          \
                GLOAD16(gv, &V_lds[g2][BUF][cid * 8]);                                    \
            }                                                                             \
        }                                                                                 \
    }

    // prologue: 2-deep prefetch; drain stage(0) (leave stage(1) in flight)
    STAGE(0, 0);
    STAGE(1, 1);
    asm volatile("s_waitcnt vmcnt(8)" ::: "memory");
    __builtin_amdgcn_s_barrier();

    for (int t = 0; t < 16; ++t) {
        const int buf = t & 1;

        // ---- batched K fragment reads (buf is safe: B2 of prev tile) ----
        const u16* kb = &K_lds[g][buf][0];
        bf8_t kf[16];
        #pragma unroll
        for (int tc = 0; tc < 16; tc++)
            kf[tc] = *(const bf8_t*)(kb + ((tc * 2 + hi) * 32 + lq) * 8);

        // ---- QK^T: S^T[32kv][32q] ----
        f16x_t s0 = (f16x_t)0.0f, s1 = (f16x_t)0.0f;
        __builtin_amdgcn_s_setprio(1);
        #pragma unroll
        for (int tc = 0; tc < 8; tc++) {
            s0 = __builtin_amdgcn_mfma_f32_32x32x16_bf16(kf[2 * tc],     qf[2 * tc],     s0, 0, 0, 0);
            s1 = __builtin_amdgcn_mfma_f32_32x32x16_bf16(kf[2 * tc + 1], qf[2 * tc + 1], s1, 0, 0, 0);
        }
        __builtin_amdgcn_s_setprio(0);

        // ---- batched V fragment reads (latency hides under softmax) ----
        const u16* vb = &V_lds[g][buf][0];
        bf8_t vf[8];
        #pragma unroll
        for (int dt = 0; dt < 4; dt++) {
            int vrow = dw * 128 + dt * 32 + lq;
            vf[2 * dt]     = *(const bf8_t*)(vb + (hi * 256 + vrow) * 8);
            vf[2 * dt + 1] = *(const bf8_t*)(vb + ((2 + hi) * 256 + vrow) * 8);
        }

        f16x_t s = s0 + s1;

        // ---- lane-local online softmax (lane's q = lq; kv split across hi) ----
        float m01 = fmaxf(s[0], s[1]),   m23 = fmaxf(s[2], s[3]);
        float m45 = fmaxf(s[4], s[5]),   m67 = fmaxf(s[6], s[7]);
        float m89 = fmaxf(s[8], s[9]),   mab = fmaxf(s[10], s[11]);
        float mcd = fmaxf(s[12], s[13]), mef = fmaxf(s[14], s[15]);
        float pm = fmaxf(fmaxf(fmaxf(m01, m23), fmaxf(m45, m67)),
                         fmaxf(fmaxf(m89, mab), fmaxf(mcd, mef)));
        float tm = fmaxf(pm, __shfl_xor(pm, 32));
        if (__ballot(tm > m_r + 8.0f)) {          // defer-max THR=8 (T13)
            float mn = fmaxf(m_r, tm);
            float corr = __expf(m_r - mn);
            m_r = mn; l_r *= corr;
            #pragma unroll
            for (int dt = 0; dt < 4; dt++)
                #pragma unroll
                for (int r = 0; r < 16; r++) o_acc[dt][r] *= corr;
        }
        float sum = 0.f;
        #pragma unroll
        for (int r = 0; r < 16; r++) { s[r] = __expf(s[r] - m_r); sum += s[r]; }
        l_r += sum;

        // ---- pack P^T B-fragments ----
        unsigned pw[8];
        #pragma unroll
        for (int j = 0; j < 8; j++) pw[j] = cvt_pk_bf16(s[2 * j], s[2 * j + 1]);
        unsigned px[8];
        #pragma unroll
        for (int j = 0; j < 8; j++) px[j] = __shfl_xor((int)pw[j], 32);
        union { unsigned w[4]; bf8_t v; } f0, f1;
        if (hi == 0) {
            f0.w[0] = pw[0]; f0.w[1] = pw[1]; f0.w[2] = px[0]; f0.w[3] = px[1];
            f1.w[0] = pw[4]; f1.w[1] = pw[5]; f1.w[2] = px[4]; f1.w[3] = px[5];
        } else {
            f0.w[0] = px[2]; f0.w[1] = px[3]; f0.w[2] = pw[2]; f0.w[3] = pw[3];
            f1.w[0] = px[6]; f1.w[1] = px[7]; f1.w[2] = pw[6]; f1.w[3] = pw[7];
        }

        // ---- B1: all our LDS reads of buf complete -> safe to overwrite ----
        asm volatile("s_waitcnt lgkmcnt(0)" ::: "memory");
        __builtin_amdgcn_s_barrier();
        if (t < 14) STAGE(t + 2, buf);

        // ---- PV: O^T[d][q] += V^T[d][kv] P^T[kv][q] (all operands in regs) ----
        __builtin_amdgcn_s_setprio(1);
        #pragma unroll
        for (int dt = 0; dt < 4; dt++) {
            o_acc[dt] = __builtin_amdgcn_mfma_f32_32x32x16_bf16(vf[2 * dt],     f0.v, o_acc[dt], 0, 0, 0);
            o_acc[dt] = __builtin_amdgcn_mfma_f32_32x32x16_bf16(vf[2 * dt + 1], f1.v, o_acc[dt], 0, 0, 0);
        }
        __builtin_amdgcn_s_setprio(0);

        // ---- B2: stage(t+1) landed in every wave -> next tile may read ----
        if (t < 15) {
            if (t < 14) { asm volatile("s_waitcnt vmcnt(8)" ::: "memory"); }
            else        { asm volatile("s_waitcnt vmcnt(0)" ::: "memory"); }
            __builtin_amdgcn_s_barrier();
        }
    }

    __syncthreads();   // all waves out of the loop before LDS reuse

    // ---- stage 1: g==1 waves park raw partials + stats in K_lds ----
    float l_tot = l_r + __shfl_xor(l_r, 32);
    float* obuf = (float*)&K_lds[0][0][0];               // 4 x 4096 f32 = 64 KB
    float* rb = obuf + (qw * 2 + dw) * 4096;
    if (g == 1) {
        #pragma unroll
        for (int dt = 0; dt < 4; dt++)
            #pragma unroll
            for (int r = 0; r < 16; r++) {
                int drow = dt * 32 + (r & 3) + 8 * (r >> 2) + 4 * hi;
                rb[drow * 32 + lq] = o_acc[dt][r];
            }
        if (dw == 0 && hi == 0) { mstat[qw][lq] = m_r; lstat[qw][lq] = l_tot; }
    }
    __syncthreads();

    // prefetch proj weight fragments (L2-hot; latency hides under merge)
    bf8_t wpf[16];
    #pragma unroll
    for (int tc = 0; tc < 16; tc++)
        wpf[tc] = *(const bf8_t*)(wpt + (((tc * 2 + hi) * 256) + wv * 32 + lq) * 8);

    // ---- stage 2: g==0 waves merge, write O tile bf16 to LDS [d>>3][64n][8] ----
    u16* O16 = (u16*)&V_lds[0][0][0];                    // 32 KB
    if (g == 0) {
        float m1 = mstat[qw][lq], l1 = lstat[qw][lq];
        float mm = fmaxf(m_r, m1);
        float a0 = __expf(m_r - mm), a1 = __expf(m1 - mm);
        float inv = 1.0f / (a0 * l_tot + a1 * l1);
        #pragma unroll
        for (int dt = 0; dt < 4; dt++)
            #pragma unroll
            for (int r = 0; r < 16; r++) {
                int drow = dt * 32 + (r & 3) + 8 * (r >> 2) + 4 * hi;
                int d = dw * 128 + drow;
                float val = (a0 * o_acc[dt][r] + a1 * rb[drow * 32 + lq]) * inv;
                O16[((d >> 3) * 64 + qw * 32 + lq) * 8 + (d & 7)] = f2bf(val);
            }
    }
    __syncthreads();

    // ---- stage 3: all 8 waves: proj GEMM out = wp x O^T + bp + x ----
    // wave wv owns c rows wv*32..+31; two n sub-tiles of 32
    f16x_t p0 = (f16x_t)0.0f, p1 = (f16x_t)0.0f;
    __builtin_amdgcn_s_setprio(1);
    #pragma unroll
    for (int tc = 0; tc < 16; tc++) {
        bf8_t of0 = *(const bf8_t*)(O16 + ((tc * 2 + hi) * 64 + lq) * 8);
        bf8_t of1 = *(const bf8_t*)(O16 + ((tc * 2 + hi) * 64 + 32 + lq) * 8);
        p0 = __builtin_amdgcn_mfma_f32_32x32x16_bf16(wpf[tc], of0, p0, 0, 0, 0);
        p1 = __builtin_amdgcn_mfma_f32_32x32x16_bf16(wpf[tc], of1, p1, 0, 0, 0);
    }
    __builtin_amdgcn_s_setprio(0);
    #pragma unroll
    for (int r = 0; r < 16; r++) {
        int crow = wv * 32 + (r & 3) + 8 * (r >> 2) + 4 * hi;
        size_t base = ((size_t)b * 256 + crow) * 1024 + qb * 64;
        float bpv = bp[crow];
        out[base + lq]      = p0[r] + bpv + x[base + lq];
        out[base + 32 + lq] = p1[r] + bpv + x[base + 32 + lq];
    }
#undef STAGE
}

extern "C" void kernel_launch(void* const* d_in, const int* in_sizes, int n_in,
                              void* d_out, int out_size, void* d_ws, size_t ws_size,
                              hipStream_t stream) {
    (void)in_sizes; (void)n_in; (void)out_size; (void)ws_size;
    const float* x   = (const float*)d_in[0];
    const float* lnw = (const float*)d_in[1];
    const float* lnb = (const float*)d_in[2];
    const float* wq  = (const float*)d_in[3];
    const float* bq  = (const float*)d_in[4];
    const float* wk  = (const float*)d_in[5];
    const float* bk  = (const float*)d_in[6];
    const float* wv  = (const float*)d_in[7];
    const float* bv  = (const float*)d_in[8];
    const float* wp  = (const float*)d_in[9];
    const float* bp  = (const float*)d_in[10];
    float* out = (float*)d_out;

    char* ws = (char*)d_ws;
    u16*   wcat  = (u16*)(ws);              // 768*256 bf16 (384KB)
    u16*   wpt   = (u16*)(ws + 0x60000);    // [32][256][8] bf16 (128KB)
    float* biasc = (float*)(ws + 0x80000);  // 768 f32
    u16*   hn    = (u16*)(ws + 0x90000);    // 16384*256 bf16   (8MB)
    u16*   qbuf  = (u16*)(ws + 0x890000);   // 16384*256 bf16   (8MB)
    u16*   kt    = (u16*)(ws + 0x1090000);  // [16][32][1024][8] bf16 (8MB)
    u16*   vt3   = (u16*)(ws + 0x1890000);  // [16][128][256][8] bf16 (8MB)

    prep_kernel<<<1028, 256, 0, stream>>>(wq, wk, wv, wp, bq, bk, bv, wcat, wpt, biasc);
    ln_kernel<<<256, 512, 0, stream>>>(x, lnw, lnb, hn);
    // QKV: [16384,768] = hn x wcat^T; epilogue routes Q/K/V into qbuf/kt/vt3
    gemm_qkv<<<dim3(128, 6, 1), 256, 0, stream>>>(hn, wcat, qbuf, biasc, kt, vt3);
    // fused attention + proj (+bias +residual)
    flash_kernel<<<256, 512, 0, stream>>>(qbuf, kt, vt3, wpt, bp, x, out);
}